// Round 7
// baseline (236.902 us; speedup 1.0000x reference)
//
#include <hip/hip_runtime.h>
#include <hip/hip_bf16.h>
#include <stdint.h>

// ---------------------------------------------------------------------------
// MappingNetwork: backbone 4x(Linear+ReLU) [16->128, 3x 128->128], then the
// selected expert head only (4 layers, last no-ReLU, 128->64).
//
// Round-7: 32-SAMPLE WAVES so the register-resident pipeline actually fits.
// r6 post-mortem: 64-sample waves need ~330 live VGPRs; compiler allocated
// 176 and re-materialized W loads at point-of-use, exposing ~400cyc L2
// latency per load pair (measured 8.4K cyc/wave-layer vs 1.5K issue work).
// With 32 samples/wave the live set is ~210 (af 32 + naf 32 + acc 32 +
// whi dbuf 64 + wlo JIT 32 + addr) -> fits under the 256 cap of
// __launch_bounds__(64,2), and wave count doubles (8-9 waves/CU TLP).
//
// Numerics (validated r3-r6, absmax 1.5259e-5): acts f16, W exact 2-term
// split w = whi + (wlo*1024)/1024 in separate accumulators.
// Operand swap mfma(W, act): D col = sample, regs = feature.
// Layout transform between layers: shfl_xor(32) pair exchange (HW-verified).
// No LDS on the hot path, no barriers.
// ---------------------------------------------------------------------------

typedef _Float16 f16;
typedef __attribute__((ext_vector_type(8)))  _Float16 f16x8;
typedef __attribute__((ext_vector_type(16))) float    f32x16;
typedef uint32_t u32;

#define MFMA(a, b, c) __builtin_amdgcn_mfma_f32_32x32x16_f16((a), (b), (c), 0, 0, 0)

constexpr int Bc = 65536;
constexpr int Kc = 16;     // experts
constexpr int Hc = 128;
constexpr int Dc = 64;

constexpr int SW   = 32;             // samples per wave
constexpr int CAP  = 4608;           // slots/expert = mean 4096 + 8.3 sigma
constexpr int WPE  = CAP / SW;       // 144 head waves per expert
constexpr int NBLK = Kc * WPE;       // 2304 one-wave blocks

constexpr float INV_LOSCALE = 1.0f / 1024.0f;

constexpr int BBW_F16 = 2048 + 3 * 16384;   // backbone weights (f16 elems)
constexpr int HWE_F16 = 3 * 16384 + 8192;   // per-expert head weights

union F8U { f16x8 v; u32 u[4]; };
union P2U { u32 u; f16 h[2]; };

__device__ __forceinline__ f32x16 zero16() {
    f32x16 z;
#pragma unroll
    for (int i = 0; i < 16; ++i) z[i] = 0.0f;
    return z;
}

__device__ __forceinline__ u32 pack2(float a, float b) {
    P2U x; x.h[0] = (f16)a; x.h[1] = (f16)b; return x.u;
}

// ---------------------------------------------------------------------------
// One 128-out Linear+ReLU layer, 32 samples, fully in registers.
// af: input B-frags [ks]; naf: output B-frags. W layout [n][KD] f16 k-fast.
// whi double-buffered across nt (prefetch hides L2); wlo loaded at nt start
// (just-in-time, ~64+ cyc of aH-MFMA work before first use).
// ---------------------------------------------------------------------------
template<int KSTEPS>
__device__ __forceinline__ void layer_reg(
    const f16* __restrict__ WHi, const f16* __restrict__ WLo,
    const float* __restrict__ bias,
    const f16x8 (&af)[8], f16x8 (&naf)[8], int l31, int bh)
{
    constexpr int KD = KSTEPS * 16;
    const f16* wpb = WHi + (size_t)l31 * KD + 8 * bh;   // +32-row steps per nt
    const f16* wqb = WLo + (size_t)l31 * KD + 8 * bh;

    f16x8 whi[2][KSTEPS];
#pragma unroll
    for (int ks = 0; ks < KSTEPS; ++ks)
        whi[0][ks] = *(const f16x8*)(wpb + ks * 16);

#pragma unroll
    for (int nt = 0; nt < 4; ++nt) {
        const int cur = nt & 1, nxt = cur ^ 1;

        // wlo for this nt: issue all loads up front (JIT, waits amortized)
        f16x8 wlo[KSTEPS];
        {
            const size_t roff = (size_t)nt * 32 * KD;
#pragma unroll
            for (int ks = 0; ks < KSTEPS; ++ks)
                wlo[ks] = *(const f16x8*)(wqb + roff + ks * 16);
        }
        // prefetch next nt's whi during this nt's compute
        if (nt < 3) {
            const size_t poff = (size_t)(nt + 1) * 32 * KD;
#pragma unroll
            for (int ks = 0; ks < KSTEPS; ++ks)
                whi[nxt][ks] = *(const f16x8*)(wpb + poff + ks * 16);
        }

        f32x16 aH = zero16(), aL = zero16();
#pragma unroll
        for (int ks = 0; ks < KSTEPS; ++ks)
            aH = MFMA(whi[cur][ks], af[ks], aH);
#pragma unroll
        for (int ks = 0; ks < KSTEPS; ++ks)
            aL = MFMA(wlo[ks], af[ks], aL);

        // epilogue: combine + bias + ReLU + pack f16x2, then pair-exchange
        u32 w[8];
#pragma unroll
        for (int rg = 0; rg < 4; ++rg) {
            const float4 bv = *(const float4*)(bias + 32 * nt + 8 * rg + 4 * bh);
            float v0 = fmaf(aL[4 * rg + 0], INV_LOSCALE, aH[4 * rg + 0]) + bv.x;
            float v1 = fmaf(aL[4 * rg + 1], INV_LOSCALE, aH[4 * rg + 1]) + bv.y;
            float v2 = fmaf(aL[4 * rg + 2], INV_LOSCALE, aH[4 * rg + 2]) + bv.z;
            float v3 = fmaf(aL[4 * rg + 3], INV_LOSCALE, aH[4 * rg + 3]) + bv.w;
            v0 = fmaxf(v0, 0.0f); v1 = fmaxf(v1, 0.0f);
            v2 = fmaxf(v2, 0.0f); v3 = fmaxf(v3, 0.0f);
            w[2 * rg]     = pack2(v0, v1);
            w[2 * rg + 1] = pack2(v2, v3);
        }
        // exchange between lanes (l31, bh=0) <-> (l31, bh=1)
#pragma unroll
        for (int k1 = 0; k1 < 2; ++k1) {
            const u32 ownA = bh ? w[2 + 4 * k1] : w[0 + 4 * k1];
            const u32 ownB = bh ? w[3 + 4 * k1] : w[1 + 4 * k1];
            const u32 sA   = bh ? w[0 + 4 * k1] : w[2 + 4 * k1];
            const u32 sB   = bh ? w[1 + 4 * k1] : w[3 + 4 * k1];
            const u32 rA = __shfl_xor(sA, 32, 64);
            const u32 rB = __shfl_xor(sB, 32, 64);
            F8U o;
            o.u[0] = bh ? rA : ownA;
            o.u[1] = bh ? rB : ownB;
            o.u[2] = bh ? ownA : rA;
            o.u[3] = bh ? ownB : rB;
            naf[2 * nt + k1] = o.v;
        }
    }
}

// ---------------------------------------------------------------------------
// Backbone: one wave per 32 samples; z -> 4 layers (registers) -> h stored in
// B-frag layout to hHi (d_out region); fused expert scatter at the tail.
// ---------------------------------------------------------------------------
__global__ __launch_bounds__(64, 2) void backbone_mfma(
    const float* __restrict__ z, const int* __restrict__ y,
    const f16* __restrict__ bbH, const f16* __restrict__ bbL,
    const float* __restrict__ bb0, const float* __restrict__ bb1,
    const float* __restrict__ bb2, const float* __restrict__ bb3,
    f16* __restrict__ hHi, int* __restrict__ idxb, int* __restrict__ cursor)
{
    const int lane = threadIdx.x;
    const int l31 = lane & 31, bh = lane >> 5;
    const int s0 = blockIdx.x * SW;

    f16x8 af[8], naf[8];

    // z -> af[0]: lane (l31,bh) holds z[s0+l31][8bh..8bh+7] as f16
    {
        const float* zp = z + (size_t)(s0 + l31) * 16 + 8 * bh;
        const float4 a0 = *(const float4*)(zp);
        const float4 a1 = *(const float4*)(zp + 4);
        f16x8 t;
        t[0] = (f16)a0.x; t[1] = (f16)a0.y; t[2] = (f16)a0.z; t[3] = (f16)a0.w;
        t[4] = (f16)a1.x; t[5] = (f16)a1.y; t[6] = (f16)a1.z; t[7] = (f16)a1.w;
        af[0] = t;
    }

    layer_reg<1>(bbH,         bbL,         bb0, af,  naf, l31, bh);
    layer_reg<8>(bbH + 2048,  bbL + 2048,  bb1, naf, af,  l31, bh);
    layer_reg<8>(bbH + 18432, bbL + 18432, bb2, af,  naf, l31, bh);
    layer_reg<8>(bbH + 34816, bbL + 34816, bb3, naf, af,  l31, bh);

    // store h in B-frag layout: hHi[b*128 + 16ks + 8bh .. +7] = af[ks]
    {
        f16* hp = hHi + (size_t)(s0 + l31) * Hc + 8 * bh;
#pragma unroll
        for (int ks = 0; ks < 8; ++ks)
            *(f16x8*)(hp + ks * 16) = af[ks];
    }

    // fused scatter (tiny LDS, end of kernel, 1-wave block)
    __shared__ int lc[Kc];
    __shared__ int lbase[Kc];
    if (lane < Kc) lc[lane] = 0;
    __syncthreads();
    int e = 0, r = 0;
    if (lane < SW) {
        e = y[s0 + lane];
        r = atomicAdd(&lc[e], 1);
    }
    __syncthreads();
    if (lane < Kc) lbase[lane] = atomicAdd(&cursor[lane], lc[lane]);
    __syncthreads();
    if (lane < SW) {
        const int slot = lbase[e] + r;
        if (slot < CAP) idxb[e * CAP + slot] = s0 + lane;
    }
}

// ---------------------------------------------------------------------------
// Heads: one wave per 32 samples of one expert, all in registers.
// Gather h B-frags directly (b128 loads), 3 reg-layers, final 128->64 with
// direct float4 stores to out[b]. hHi aliases d_out (row-disjoint, read-first).
// ---------------------------------------------------------------------------
__global__ __launch_bounds__(64, 2) void heads_mfma(
    const f16* hHi,
    const int* __restrict__ idxb, const int* __restrict__ cursor,
    const f16* __restrict__ hH, const f16* __restrict__ hL,
    const float* __restrict__ hb0, const float* __restrict__ hb1,
    const float* __restrict__ hb2, const float* __restrict__ hb3,
    float* out)
{
    const int blk = blockIdx.x;
    const int e = blk / WPE;
    const int local0 = (blk % WPE) * SW;
    const int cnt = min(cursor[e], CAP);
    const int nvalid = cnt - local0;
    if (nvalid <= 0) return;

    const int lane = threadIdx.x;
    const int l31 = lane & 31, bh = lane >> 5;

    f16x8 af[8], naf[8];
    const int myb = (l31 < nvalid) ? idxb[e * CAP + local0 + l31] : -1;

    if (myb >= 0) {
        const f16* hp = hHi + (size_t)myb * Hc + 8 * bh;
#pragma unroll
        for (int ks = 0; ks < 8; ++ks)
            af[ks] = *(const f16x8*)(hp + ks * 16);
    } else {
        f16x8 zz;
#pragma unroll
        for (int j = 0; j < 8; ++j) zz[j] = (f16)0.0f;
#pragma unroll
        for (int ks = 0; ks < 8; ++ks) af[ks] = zz;
    }

    const size_t we = (size_t)e * HWE_F16;
    layer_reg<8>(hH + we,         hL + we,         hb0 + e * Hc, af,  naf, l31, bh);
    layer_reg<8>(hH + we + 16384, hL + we + 16384, hb1 + e * Hc, naf, af,  l31, bh);
    layer_reg<8>(hH + we + 32768, hL + we + 32768, hb2 + e * Hc, af,  naf, l31, bh);

    // final layer: 128 -> 64, no ReLU, whi dbuf + wlo JIT, float4 stores
    {
        const f16* wpb = hH + we + 49152 + (size_t)l31 * 128 + 8 * bh;
        const f16* wqb = hL + we + 49152 + (size_t)l31 * 128 + 8 * bh;
        const float* bias = hb3 + e * Dc;

        f16x8 whi[2][8];
#pragma unroll
        for (int ks = 0; ks < 8; ++ks)
            whi[0][ks] = *(const f16x8*)(wpb + ks * 16);

#pragma unroll
        for (int nt = 0; nt < 2; ++nt) {
            const int cur = nt & 1, nxt = cur ^ 1;
            f16x8 wlo[8];
            {
                const size_t roff = (size_t)nt * 32 * 128;
#pragma unroll
                for (int ks = 0; ks < 8; ++ks)
                    wlo[ks] = *(const f16x8*)(wqb + roff + ks * 16);
            }
            if (nt < 1) {
#pragma unroll
                for (int ks = 0; ks < 8; ++ks)
                    whi[nxt][ks] = *(const f16x8*)(wpb + (size_t)32 * 128 + ks * 16);
            }
            f32x16 aH = zero16(), aL = zero16();
#pragma unroll
            for (int ks = 0; ks < 8; ++ks)
                aH = MFMA(whi[cur][ks], naf[ks], aH);
#pragma unroll
            for (int ks = 0; ks < 8; ++ks)
                aL = MFMA(wlo[ks], naf[ks], aL);

            if (myb >= 0) {
#pragma unroll
                for (int rg = 0; rg < 4; ++rg) {
                    const int nb = 32 * nt + 8 * rg + 4 * bh;
                    const float4 bv = *(const float4*)(bias + nb);
                    float4 v;
                    v.x = fmaf(aL[rg * 4 + 0], INV_LOSCALE, aH[rg * 4 + 0]) + bv.x;
                    v.y = fmaf(aL[rg * 4 + 1], INV_LOSCALE, aH[rg * 4 + 1]) + bv.y;
                    v.z = fmaf(aL[rg * 4 + 2], INV_LOSCALE, aH[rg * 4 + 2]) + bv.z;
                    v.w = fmaf(aL[rg * 4 + 3], INV_LOSCALE, aH[rg * 4 + 3]) + bv.w;
                    *(float4*)(out + (size_t)myb * Dc + nb) = v;
                }
            }
        }
    }
}

// ---------------------------------------------------------------------------
// Weight prep: split fp32 W[k][n] -> f16 hi + f16 (lo*1024), transposed to
// Wt[n][k]. One block per 32x32 tile. Block 0 also zeroes the scatter cursor.
// ---------------------------------------------------------------------------
__global__ void prep_w(
    const float* __restrict__ bw0, const float* __restrict__ bw1,
    const float* __restrict__ bw2, const float* __restrict__ bw3,
    const float* __restrict__ hw0, const float* __restrict__ hw1,
    const float* __restrict__ hw2, const float* __restrict__ hw3,
    f16* __restrict__ bbH, f16* __restrict__ bbL,
    f16* __restrict__ hH,  f16* __restrict__ hL,
    int* __restrict__ cursor)
{
    __shared__ float T[32][33];
    const int id = blockIdx.x;
    const int tx = threadIdx.x;

    if (id == 0 && tx < Kc) cursor[tx] = 0;

    const float* src; f16 *dh, *dl;
    int K, N, KD, k0, n0;

    if (id < 52) {
        if (id < 4) {
            src = bw0; dh = bbH; dl = bbL;
            K = 16; N = 128; KD = 16; k0 = 0; n0 = id * 32;
        } else {
            const int t = id - 4;
            const int l = t / 16, tile = t % 16;
            const float* bws[3] = {bw1, bw2, bw3};
            src = bws[l];
            dh = bbH + 2048 + l * 16384;
            dl = bbL + 2048 + l * 16384;
            K = 128; N = 128; KD = 128;
            k0 = (tile >> 2) * 32; n0 = (tile & 3) * 32;
        }
    } else {
        const int t = id - 52;
        const int e = t / 56, r = t % 56;
        if (r < 48) {
            const int l = r / 16, tile = r % 16;
            const float* hws[3] = {hw0, hw1, hw2};
            src = hws[l] + (size_t)e * 16384;
            dh = hH + (size_t)e * HWE_F16 + l * 16384;
            dl = hL + (size_t)e * HWE_F16 + l * 16384;
            K = 128; N = 128; KD = 128;
            k0 = (tile >> 2) * 32; n0 = (tile & 3) * 32;
        } else {
            const int r2 = r - 48;
            src = hw3 + (size_t)e * 8192;
            dh = hH + (size_t)e * HWE_F16 + 49152;
            dl = hL + (size_t)e * HWE_F16 + 49152;
            K = 128; N = 64; KD = 128;
            k0 = (r2 >> 1) * 32; n0 = (r2 & 1) * 32;
        }
    }

    const int c = tx & 31, g = tx >> 5;
#pragma unroll
    for (int i = 0; i < 4; ++i) {
        const int row = g * 4 + i;
        if (k0 + row < K)
            T[c][row] = src[(size_t)(k0 + row) * N + n0 + c];   // T[n-local][k-local]
    }
    __syncthreads();
#pragma unroll
    for (int i = 0; i < 4; ++i) {
        const int n = g * 4 + i;
        if (k0 + c < K) {
            const float v = T[n][c];
            const f16 hi = (f16)v;
            dh[(size_t)(n0 + n) * KD + k0 + c] = hi;
            dl[(size_t)(n0 + n) * KD + k0 + c] = (f16)((v - (float)hi) * 1024.0f);
        }
    }
}

// ---------------------------------------------------------------------------
extern "C" void kernel_launch(void* const* d_in, const int* in_sizes, int n_in,
                              void* d_out, int out_size, void* d_ws, size_t ws_size,
                              hipStream_t stream)
{
    const float* z   = (const float*)d_in[0];
    const int*   y   = (const int*)d_in[1];
    const float* bw0 = (const float*)d_in[2];
    const float* bb0 = (const float*)d_in[3];
    const float* bw1 = (const float*)d_in[4];
    const float* bb1 = (const float*)d_in[5];
    const float* bw2 = (const float*)d_in[6];
    const float* bb2 = (const float*)d_in[7];
    const float* bw3 = (const float*)d_in[8];
    const float* bb3 = (const float*)d_in[9];
    const float* hw0 = (const float*)d_in[10];
    const float* hb0 = (const float*)d_in[11];
    const float* hw1 = (const float*)d_in[12];
    const float* hb1 = (const float*)d_in[13];
    const float* hw2 = (const float*)d_in[14];
    const float* hb2 = (const float*)d_in[15];
    const float* hw3 = (const float*)d_in[16];
    const float* hb3 = (const float*)d_in[17];
    float* out = (float*)d_out;

    // h (f16 [B][128], B-frag layout) aliases d_out exactly: sample b's h row
    // and out row occupy the same 256-byte range; gather precedes store.
    f16* hHi = (f16*)d_out;

    // workspace layout (segments 256B-aligned)
    char* p = (char*)d_ws;
    f16* bbH = (f16*)p;  p += (size_t)BBW_F16 * 2;
    f16* bbL = (f16*)p;  p += (size_t)BBW_F16 * 2;
    f16* hH  = (f16*)p;  p += (size_t)Kc * HWE_F16 * 2;
    f16* hL  = (f16*)p;  p += (size_t)Kc * HWE_F16 * 2;
    int* idxb = (int*)p; p += (size_t)Kc * CAP * 4;
    int* cursor = (int*)p;

    prep_w<<<52 + Kc * 56, 256, 0, stream>>>(bw0, bw1, bw2, bw3,
                                             hw0, hw1, hw2, hw3,
                                             bbH, bbL, hH, hL, cursor);

    backbone_mfma<<<Bc / SW, 64, 0, stream>>>(z, y, bbH, bbL,
                                              bb0, bb1, bb2, bb3,
                                              hHi, idxb, cursor);

    heads_mfma<<<NBLK, 64, 0, stream>>>(hHi, idxb, cursor,
                                        hH, hL, hb0, hb1, hb2, hb3, out);
}

// Round 8
// 190.470 us; speedup vs baseline: 1.2438x; 1.2438x over previous
//
#include <hip/hip_runtime.h>
#include <hip/hip_bf16.h>
#include <stdint.h>

// ---------------------------------------------------------------------------
// MappingNetwork: backbone 4x(Linear+ReLU) [16->128, 3x 128->128], then the
// selected expert head only (4 layers, last no-ReLU, 128->64).
//
// Round-8: W streamed via global_load_lds DMA ring (3 x 16KB LDS slots,
// staged 2 phases ahead, explicit s_waitcnt vmcnt(16)). DMA queue depth is
// independent of VGPRs — r2-r7 all flatlined because the compiler would not
// hold >1 chunk of W in registers (alloc 88-176 vs ~300 live), serializing
// L2 round trips. Activations stay register-resident (64 samples/wave,
// shfl_xor relayout, validated r5-r7). Biases preloaded to LDS so no global
// loads pollute vmcnt inside the pipeline (would force vmcnt(0) drains).
// W is stored PRE-SWIZZLED in global (u ^= n&15 on 16B units) so the linear
// DMA copy yields a conflict-floor LDS layout for ds_read_b128.
//
// Numerics (validated r3-r7, absmax 1.5259e-5): acts f16, W exact 2-term
// split w = whi + (wlo*1024)/1024 in separate accumulators.
// ---------------------------------------------------------------------------

typedef _Float16 f16;
typedef __attribute__((ext_vector_type(8)))  _Float16 f16x8;
typedef __attribute__((ext_vector_type(16))) float    f32x16;
typedef uint32_t u32;

#define MFMA(a, b, c) __builtin_amdgcn_mfma_f32_32x32x16_f16((a), (b), (c), 0, 0, 0)

// s_waitcnt: vmcnt low4 [3:0], hi2 [15:14]; expcnt=7 (off) [6:4]; lgkmcnt=15 (off) [11:8]
#define WAIT_VM16() { __builtin_amdgcn_s_waitcnt(0x4F70); asm volatile("" ::: "memory"); }
#define WAIT_VM0()  { __builtin_amdgcn_s_waitcnt(0x0F70); asm volatile("" ::: "memory"); }

#define GLL(g, l) __builtin_amdgcn_global_load_lds( \
    (const __attribute__((address_space(1))) unsigned int*)(const void*)(g), \
    (__attribute__((address_space(3))) unsigned int*)(void*)(l), 16, 0, 0)

constexpr int Bc = 65536;
constexpr int Kc = 16;     // experts
constexpr int Hc = 128;
constexpr int Dc = 64;

constexpr int CAP  = 4608;           // slots/expert = mean 4096 + 8.3 sigma
constexpr int WPE  = CAP / 64;       // 72 head waves per expert
constexpr int NBLK = Kc * WPE;       // 1152 one-wave blocks

constexpr float INV_LOSCALE = 1.0f / 1024.0f;

constexpr int BBW_F16 = 2048 + 12 * 4096;   // backbone: l0 linear + 12 chunks
constexpr int HWE_F16 = 14 * 4096;          // per expert: 14 chunks (l0-2 + final)

union F8U { f16x8 v; u32 u[4]; };
union P2U { u32 u; f16 h[2]; };

__device__ __forceinline__ f32x16 zero16() {
    f32x16 z;
#pragma unroll
    for (int i = 0; i < 16; ++i) z[i] = 0.0f;
    return z;
}

__device__ __forceinline__ u32 pack2(float a, float b) {
    P2U x; x.h[0] = (f16)a; x.h[1] = (f16)b; return x.u;
}

// stage one 16KB chunk (8KB hi + 8KB lo) into an LDS ring slot: 16 DMA instrs
__device__ __forceinline__ void stage16(const f16* hi, const f16* lo,
                                        f16* slot, int lane)
{
#pragma unroll
    for (int j = 0; j < 8; ++j)
        GLL(hi + j * 512 + lane * 8, slot + j * 512);
#pragma unroll
    for (int j = 0; j < 8; ++j)
        GLL(lo + j * 512 + lane * 8, slot + 4096 + j * 512);
}

// epilogue: combine hi/lo acc + bias(+ReLU) + pack f16 + shfl_xor(32) pair
// exchange into B-frag layout (validated r5-r7)
__device__ __forceinline__ void epi_relayout(
    const f32x16 (&aH)[2], const f32x16 (&aL)[2],
    const float* biasLds, int nt, f16x8 (&OUT)[2][8], int bh)
{
#pragma unroll
    for (int mt = 0; mt < 2; ++mt) {
        u32 w[8];
#pragma unroll
        for (int rg = 0; rg < 4; ++rg) {
            const float4 bv = *(const float4*)(biasLds + 32 * nt + 8 * rg + 4 * bh);
            float v0 = fmaf(aL[mt][4 * rg + 0], INV_LOSCALE, aH[mt][4 * rg + 0]) + bv.x;
            float v1 = fmaf(aL[mt][4 * rg + 1], INV_LOSCALE, aH[mt][4 * rg + 1]) + bv.y;
            float v2 = fmaf(aL[mt][4 * rg + 2], INV_LOSCALE, aH[mt][4 * rg + 2]) + bv.z;
            float v3 = fmaf(aL[mt][4 * rg + 3], INV_LOSCALE, aH[mt][4 * rg + 3]) + bv.w;
            v0 = fmaxf(v0, 0.0f); v1 = fmaxf(v1, 0.0f);
            v2 = fmaxf(v2, 0.0f); v3 = fmaxf(v3, 0.0f);
            w[2 * rg]     = pack2(v0, v1);
            w[2 * rg + 1] = pack2(v2, v3);
        }
#pragma unroll
        for (int k1 = 0; k1 < 2; ++k1) {
            const u32 ownA = bh ? w[2 + 4 * k1] : w[0 + 4 * k1];
            const u32 ownB = bh ? w[3 + 4 * k1] : w[1 + 4 * k1];
            const u32 sA   = bh ? w[0 + 4 * k1] : w[2 + 4 * k1];
            const u32 sB   = bh ? w[1 + 4 * k1] : w[3 + 4 * k1];
            const u32 rA = __shfl_xor(sA, 32, 64);
            const u32 rB = __shfl_xor(sB, 32, 64);
            F8U o;
            o.u[0] = bh ? rA : ownA;
            o.u[1] = bh ? rB : ownB;
            o.u[2] = bh ? ownA : rA;
            o.u[3] = bh ? ownB : rB;
            OUT[mt][2 * nt + k1] = o.v;
        }
    }
}

// consume one staged chunk: 16 ds_read_b128 (swizzled) + 32 MFMA + epilogue
__device__ __forceinline__ void consume_nt(
    const f16* slot, const float* biasLds, int nt,
    const f16x8 (&IN)[2][8], f16x8 (&OUT)[2][8], int l31, int bh)
{
    f32x16 aH[2], aL[2];
    aH[0] = zero16(); aH[1] = zero16();
    aL[0] = zero16(); aL[1] = zero16();
    const int sw = l31 & 15;
#pragma unroll
    for (int ks = 0; ks < 8; ++ks) {
        const int u = (2 * ks + bh) ^ sw;
        const f16x8 whi = *(const f16x8*)(slot + l31 * 128 + u * 8);
        const f16x8 wlo = *(const f16x8*)(slot + 4096 + l31 * 128 + u * 8);
#pragma unroll
        for (int mt = 0; mt < 2; ++mt) {
            aH[mt] = MFMA(whi, IN[mt][ks], aH[mt]);
            aL[mt] = MFMA(wlo, IN[mt][ks], aL[mt]);
        }
    }
    epi_relayout(aH, aL, biasLds, nt, OUT, bh);
}

// final head layer chunk (32 out-cols): MFMA + direct float4 stores
__device__ __forceinline__ void consume_final(
    const f16* slot, const float* biasLds, int nt,
    const f16x8 (&IN)[2][8], const int (&myb)[2], float* out, int l31, int bh)
{
    f32x16 aH[2], aL[2];
    aH[0] = zero16(); aH[1] = zero16();
    aL[0] = zero16(); aL[1] = zero16();
    const int sw = l31 & 15;
#pragma unroll
    for (int ks = 0; ks < 8; ++ks) {
        const int u = (2 * ks + bh) ^ sw;
        const f16x8 whi = *(const f16x8*)(slot + l31 * 128 + u * 8);
        const f16x8 wlo = *(const f16x8*)(slot + 4096 + l31 * 128 + u * 8);
#pragma unroll
        for (int mt = 0; mt < 2; ++mt) {
            aH[mt] = MFMA(whi, IN[mt][ks], aH[mt]);
            aL[mt] = MFMA(wlo, IN[mt][ks], aL[mt]);
        }
    }
#pragma unroll
    for (int mt = 0; mt < 2; ++mt) {
        if (myb[mt] < 0) continue;
#pragma unroll
        for (int rg = 0; rg < 4; ++rg) {
            const int nb = 32 * nt + 8 * rg + 4 * bh;
            const float4 bv = *(const float4*)(biasLds + nb);
            float4 v;
            v.x = fmaf(aL[mt][rg * 4 + 0], INV_LOSCALE, aH[mt][rg * 4 + 0]) + bv.x;
            v.y = fmaf(aL[mt][rg * 4 + 1], INV_LOSCALE, aH[mt][rg * 4 + 1]) + bv.y;
            v.z = fmaf(aL[mt][rg * 4 + 2], INV_LOSCALE, aH[mt][rg * 4 + 2]) + bv.z;
            v.w = fmaf(aL[mt][rg * 4 + 3], INV_LOSCALE, aH[mt][rg * 4 + 3]) + bv.w;
            *(float4*)(out + (size_t)myb[mt] * Dc + nb) = v;
        }
    }
}

// phase macros: wait for chunk p (vmcnt(16): >=16 vmem issued after it),
// stage chunk p+2, consume chunk p.
#define PH_S(p, BI, NT, INA, OUTA) { WAIT_VM16(); \
    stage16(hiS + (p + 2) * 4096, loS + (p + 2) * 4096, &RING[((p + 2) % 3) * 8192], lane); \
    consume_nt(&RING[((p) % 3) * 8192], BIAS + (BI), NT, INA, OUTA, l31, bh); }
#define PH_N(p, BI, NT, INA, OUTA) { WAIT_VM16(); \
    consume_nt(&RING[((p) % 3) * 8192], BIAS + (BI), NT, INA, OUTA, l31, bh); }
#define PH_L(p, BI, NT, INA, OUTA) { WAIT_VM0(); \
    consume_nt(&RING[((p) % 3) * 8192], BIAS + (BI), NT, INA, OUTA, l31, bh); }

// ---------------------------------------------------------------------------
// Backbone: one wave per 64 samples. Layer0 (K=16) in registers; layers 1-3
// via the DMA ring (12 chunks). h stored in B-frag layout to hHi (d_out).
// ---------------------------------------------------------------------------
__global__ __launch_bounds__(64, 2) void backbone_mfma(
    const float* __restrict__ z, const int* __restrict__ y,
    const f16* __restrict__ bbH, const f16* __restrict__ bbL,
    const float* __restrict__ bb0, const float* __restrict__ bb1,
    const float* __restrict__ bb2, const float* __restrict__ bb3,
    f16* __restrict__ hHi, int* __restrict__ idxb, int* __restrict__ cursor)
{
    __shared__ __attribute__((aligned(16))) f16   RING[3 * 8192];
    __shared__ __attribute__((aligned(16))) float BIAS[512];
    __shared__ int lc[Kc];
    __shared__ int lbase[Kc];

    const int lane = threadIdx.x;
    const int l31 = lane & 31, bh = lane >> 5;
    const int s0 = blockIdx.x * 64;

    // biases -> LDS (keeps vmcnt clean inside the pipeline)
#pragma unroll
    for (int j = 0; j < 8; ++j) {
        const int i = j * 64 + lane;
        float v;
        if      (i < 128) v = bb0[i];
        else if (i < 256) v = bb1[i - 128];
        else if (i < 384) v = bb2[i - 256];
        else              v = bb3[i - 384];
        BIAS[i] = v;
    }
    __syncthreads();

    f16x8 af[2][8], naf[2][8];

    // z -> af[mt][0]
#pragma unroll
    for (int mt = 0; mt < 2; ++mt) {
        const float* zp = z + (size_t)(s0 + 32 * mt + l31) * 16 + 8 * bh;
        const float4 a0 = *(const float4*)(zp);
        const float4 a1 = *(const float4*)(zp + 4);
        f16x8 t;
        t[0] = (f16)a0.x; t[1] = (f16)a0.y; t[2] = (f16)a0.z; t[3] = (f16)a0.w;
        t[4] = (f16)a1.x; t[5] = (f16)a1.y; t[6] = (f16)a1.z; t[7] = (f16)a1.w;
        af[mt][0] = t;
    }

    // layer0 W (linear layout, tiny): preload before stages
    f16x8 w0h[4], w0l[4];
#pragma unroll
    for (int nt = 0; nt < 4; ++nt) {
        w0h[nt] = *(const f16x8*)(bbH + (32 * nt + l31) * 16 + 8 * bh);
        w0l[nt] = *(const f16x8*)(bbL + (32 * nt + l31) * 16 + 8 * bh);
    }

    const f16* hiS = bbH + 2048;   // 12-chunk contiguous stream (layers 1-3)
    const f16* loS = bbL + 2048;
    stage16(hiS,        loS,        &RING[0],    lane);
    stage16(hiS + 4096, loS + 4096, &RING[8192], lane);

    // layer0 compute (af -> naf)
#pragma unroll
    for (int nt = 0; nt < 4; ++nt) {
        f32x16 aH[2], aL[2];
        aH[0] = zero16(); aH[1] = zero16();
        aL[0] = zero16(); aL[1] = zero16();
#pragma unroll
        for (int mt = 0; mt < 2; ++mt) {
            aH[mt] = MFMA(w0h[nt], af[mt][0], aH[mt]);
            aL[mt] = MFMA(w0l[nt], af[mt][0], aL[mt]);
        }
        epi_relayout(aH, aL, BIAS, nt, naf, bh);
    }

    // layers 1-3: 12 pipelined chunks
    PH_S(0,  128, 0, naf, af)  PH_S(1,  128, 1, naf, af)
    PH_S(2,  128, 2, naf, af)  PH_S(3,  128, 3, naf, af)
    PH_S(4,  256, 0, af, naf)  PH_S(5,  256, 1, af, naf)
    PH_S(6,  256, 2, af, naf)  PH_S(7,  256, 3, af, naf)
    PH_S(8,  384, 0, naf, af)  PH_S(9,  384, 1, naf, af)
    PH_N(10, 384, 2, naf, af)  PH_L(11, 384, 3, naf, af)

    // store h in B-frag layout
#pragma unroll
    for (int mt = 0; mt < 2; ++mt) {
        f16* hp = hHi + (size_t)(s0 + 32 * mt + l31) * Hc + 8 * bh;
#pragma unroll
        for (int ks = 0; ks < 8; ++ks)
            *(f16x8*)(hp + ks * 16) = af[mt][ks];
    }

    // fused expert scatter
    if (lane < Kc) lc[lane] = 0;
    __syncthreads();
    const int e = y[s0 + lane];
    const int r = atomicAdd(&lc[e], 1);
    __syncthreads();
    if (lane < Kc) lbase[lane] = atomicAdd(&cursor[lane], lc[lane]);
    __syncthreads();
    const int slot = lbase[e] + r;
    if (slot < CAP) idxb[e * CAP + slot] = s0 + lane;
}

// ---------------------------------------------------------------------------
// Heads: one wave per 64 samples of one expert. 14 pipelined chunks
// (layers 0-2 = 12, final 128->64 = 2). hHi aliases d_out (read-first).
// ---------------------------------------------------------------------------
__global__ __launch_bounds__(64, 2) void heads_mfma(
    const f16* hHi,
    const int* __restrict__ idxb, const int* __restrict__ cursor,
    const f16* __restrict__ hH, const f16* __restrict__ hL,
    const float* __restrict__ hb0, const float* __restrict__ hb1,
    const float* __restrict__ hb2, const float* __restrict__ hb3,
    float* out)
{
    __shared__ __attribute__((aligned(16))) f16   RING[3 * 8192];
    __shared__ __attribute__((aligned(16))) float BIAS[512];

    const int blk = blockIdx.x;
    const int e = blk / WPE;
    const int local0 = (blk % WPE) * 64;
    const int cnt = min(cursor[e], CAP);
    const int nvalid = cnt - local0;
    if (nvalid <= 0) return;

    const int lane = threadIdx.x;
    const int l31 = lane & 31, bh = lane >> 5;

    // biases -> LDS
#pragma unroll
    for (int j = 0; j < 7; ++j) {
        const int i = j * 64 + lane;
        float v;
        if      (i < 128) v = hb0[e * Hc + i];
        else if (i < 256) v = hb1[e * Hc + i - 128];
        else if (i < 384) v = hb2[e * Hc + i - 256];
        else              v = hb3[e * Dc + i - 384];
        BIAS[i] = v;
    }
    __syncthreads();

    f16x8 af[2][8], naf[2][8];
    int myb[2];
#pragma unroll
    for (int mt = 0; mt < 2; ++mt) {
        const int li = 32 * mt + l31;
        myb[mt] = (li < nvalid) ? idxb[e * CAP + local0 + li] : -1;
        if (myb[mt] >= 0) {
            const f16* hp = hHi + (size_t)myb[mt] * Hc + 8 * bh;
#pragma unroll
            for (int ks = 0; ks < 8; ++ks)
                af[mt][ks] = *(const f16x8*)(hp + ks * 16);
        } else {
            f16x8 zz;
#pragma unroll
            for (int j = 0; j < 8; ++j) zz[j] = (f16)0.0f;
#pragma unroll
            for (int ks = 0; ks < 8; ++ks) af[mt][ks] = zz;
        }
    }

    const f16* hiS = hH + (size_t)e * HWE_F16;   // 14-chunk contiguous stream
    const f16* loS = hL + (size_t)e * HWE_F16;
    stage16(hiS,        loS,        &RING[0],    lane);
    stage16(hiS + 4096, loS + 4096, &RING[8192], lane);

    PH_S(0,  0,   0, af, naf)  PH_S(1,  0,   1, af, naf)
    PH_S(2,  0,   2, af, naf)  PH_S(3,  0,   3, af, naf)
    PH_S(4,  128, 0, naf, af)  PH_S(5,  128, 1, naf, af)
    PH_S(6,  128, 2, naf, af)  PH_S(7,  128, 3, naf, af)
    PH_S(8,  256, 0, af, naf)  PH_S(9,  256, 1, af, naf)
    PH_S(10, 256, 2, af, naf)  PH_S(11, 256, 3, af, naf)

    WAIT_VM16();
    consume_final(&RING[(12 % 3) * 8192], BIAS + 384, 0, naf, myb, out, l31, bh);
    WAIT_VM0();
    consume_final(&RING[(13 % 3) * 8192], BIAS + 384, 1, naf, myb, out, l31, bh);
}

// ---------------------------------------------------------------------------
// Weight prep: split fp32 W[k][n] -> f16 hi + f16 (lo*1024), transposed to
// Wt[n][k]; KD=128 matrices are stored PRE-SWIZZLED in 32-row chunks
// (16B unit u -> u ^ (n&15)) so the linear DMA copy gives conflict-floor
// ds_read_b128. Layer0 (KD=16) stays linear. Block 0 zeroes the cursor.
// ---------------------------------------------------------------------------
__global__ void prep_w(
    const float* __restrict__ bw0, const float* __restrict__ bw1,
    const float* __restrict__ bw2, const float* __restrict__ bw3,
    const float* __restrict__ hw0, const float* __restrict__ hw1,
    const float* __restrict__ hw2, const float* __restrict__ hw3,
    f16* __restrict__ bbH, f16* __restrict__ bbL,
    f16* __restrict__ hH,  f16* __restrict__ hL,
    int* __restrict__ cursor)
{
    __shared__ float T[32][33];
    const int id = blockIdx.x;
    const int tx = threadIdx.x;

    if (id == 0 && tx < Kc) cursor[tx] = 0;

    const float* src; f16 *dh, *dl;
    int K, N, k0, n0;
    bool swz;

    if (id < 52) {
        if (id < 4) {
            src = bw0; dh = bbH; dl = bbL;
            K = 16; N = 128; k0 = 0; n0 = id * 32; swz = false;
        } else {
            const int t = id - 4;
            const int l = t / 16, tile = t % 16;
            const float* bws[3] = {bw1, bw2, bw3};
            src = bws[l];
            dh = bbH + 2048 + l * 16384;
            dl = bbL + 2048 + l * 16384;
            K = 128; N = 128; swz = true;
            k0 = (tile >> 2) * 32; n0 = (tile & 3) * 32;
        }
    } else {
        const int t = id - 52;
        const int e = t / 56, r = t % 56;
        if (r < 48) {
            const int l = r / 16, tile = r % 16;
            const float* hws[3] = {hw0, hw1, hw2};
            src = hws[l] + (size_t)e * 16384;
            dh = hH + (size_t)e * HWE_F16 + l * 16384;
            dl = hL + (size_t)e * HWE_F16 + l * 16384;
            K = 128; N = 128; swz = true;
            k0 = (tile >> 2) * 32; n0 = (tile & 3) * 32;
        } else {
            const int r2 = r - 48;
            src = hw3 + (size_t)e * 8192;
            dh = hH + (size_t)e * HWE_F16 + 49152;
            dl = hL + (size_t)e * HWE_F16 + 49152;
            K = 128; N = 64; swz = true;
            k0 = (r2 >> 1) * 32; n0 = (r2 & 1) * 32;
        }
    }

    const int c = tx & 31, g = tx >> 5;
#pragma unroll
    for (int i = 0; i < 4; ++i) {
        const int row = g * 4 + i;
        if (k0 + row < K)
            T[c][row] = src[(size_t)(k0 + row) * N + n0 + c];   // T[n-local][k-local]
    }
    __syncthreads();
#pragma unroll
    for (int i = 0; i < 4; ++i) {
        const int n = g * 4 + i;
        if (k0 + c < K) {
            const float v = T[n][c];
            const f16 hi = (f16)v;
            const f16 lo = (f16)((v - (float)hi) * 1024.0f);
            size_t didx;
            if (swz) {
                const int ng = n0 + n, k = k0 + c;
                const int nl = ng & 31;
                const int u  = (k >> 3) ^ (nl & 15);
                didx = (size_t)(ng >> 5) * 4096 + nl * 128 + u * 8 + (k & 7);
            } else {
                didx = (size_t)(n0 + n) * 16 + k0 + c;
            }
            dh[didx] = hi;
            dl[didx] = lo;
        }
    }
}

// ---------------------------------------------------------------------------
extern "C" void kernel_launch(void* const* d_in, const int* in_sizes, int n_in,
                              void* d_out, int out_size, void* d_ws, size_t ws_size,
                              hipStream_t stream)
{
    const float* z   = (const float*)d_in[0];
    const int*   y   = (const int*)d_in[1];
    const float* bw0 = (const float*)d_in[2];
    const float* bb0 = (const float*)d_in[3];
    const float* bw1 = (const float*)d_in[4];
    const float* bb1 = (const float*)d_in[5];
    const float* bw2 = (const float*)d_in[6];
    const float* bb2 = (const float*)d_in[7];
    const float* bw3 = (const float*)d_in[8];
    const float* bb3 = (const float*)d_in[9];
    const float* hw0 = (const float*)d_in[10];
    const float* hb0 = (const float*)d_in[11];
    const float* hw1 = (const float*)d_in[12];
    const float* hb1 = (const float*)d_in[13];
    const float* hw2 = (const float*)d_in[14];
    const float* hb2 = (const float*)d_in[15];
    const float* hw3 = (const float*)d_in[16];
    const float* hb3 = (const float*)d_in[17];
    float* out = (float*)d_out;

    // h (f16 [B][128], B-frag layout) aliases d_out exactly: sample b's h row
    // and out row occupy the same 256-byte range; gather precedes store.
    f16* hHi = (f16*)d_out;

    // workspace layout (segments 256B-aligned)
    char* p = (char*)d_ws;
    f16* bbH = (f16*)p;  p += (size_t)BBW_F16 * 2;
    f16* bbL = (f16*)p;  p += (size_t)BBW_F16 * 2;
    f16* hH  = (f16*)p;  p += (size_t)Kc * HWE_F16 * 2;
    f16* hL  = (f16*)p;  p += (size_t)Kc * HWE_F16 * 2;
    int* idxb = (int*)p; p += (size_t)Kc * CAP * 4;
    int* cursor = (int*)p;

    prep_w<<<52 + Kc * 56, 256, 0, stream>>>(bw0, bw1, bw2, bw3,
                                             hw0, hw1, hw2, hw3,
                                             bbH, bbL, hH, hL, cursor);

    backbone_mfma<<<Bc / 64, 64, 0, stream>>>(z, y, bbH, bbL,
                                              bb0, bb1, bb2, bb3,
                                              hHi, idxb, cursor);

    heads_mfma<<<NBLK, 64, 0, stream>>>(hHi, idxb, cursor,
                                        hH, hL, hb0, hb1, hb2, hb3, out);
}

// Round 9
// 154.066 us; speedup vs baseline: 1.5377x; 1.2363x over previous
//
#include <hip/hip_runtime.h>
#include <hip/hip_bf16.h>
#include <stdint.h>

// ---------------------------------------------------------------------------
// MappingNetwork: backbone 4x(Linear+ReLU) [16->128, 3x 128->128], then the
// selected expert head only (4 layers, last no-ReLU, 128->64).
//
// Round-9: OCCUPANCY-FIRST. r2-r8 all ran <=4 waves/CU (measured 1.7 avg,
// OccupancyPercent 5-13%) — no TLP, so every latency was paid serially and
// six different structures flatlined at ~55 us/kernel. Now: 256-thread
// blocks (4 waves), 64 samples/block, each wave owns one 32-col quarter of
// every layer (small acc+W footprint -> ~130 live VGPRs < 170 cap of
// launch_bounds(256,3)) -> 12 waves/CU. Activations in a 16KB XOR-swizzled
// LDS tile (bank-conflict floor), double-buffered, ONE barrier per layer.
// W pre-laid-out per 32-row chunk as [ks][lane] so each wave load is a
// coalesced 1KB/instr L2 stream. Expert scatter moved OUT of backbone into
// a standalone kernel (its 16K same-cacheline atomics were a serial tail);
// cursor entries padded to separate cache lines.
//
// Numerics (validated r3-r8, absmax 1.5259e-5): acts f16, W exact 2-term
// split w = whi + (wlo*1024)/1024 in separate accumulators.
// MFMA operand swap mfma(W, act): D lane = sample, D regs = feature.
// ---------------------------------------------------------------------------

typedef _Float16 f16;
typedef __attribute__((ext_vector_type(4)))  _Float16 f16x4;
typedef __attribute__((ext_vector_type(8)))  _Float16 f16x8;
typedef __attribute__((ext_vector_type(16))) float    f32x16;
typedef uint32_t u32;

#define MFMA(a, b, c) __builtin_amdgcn_mfma_f32_32x32x16_f16((a), (b), (c), 0, 0, 0)

constexpr int Bc = 65536;
constexpr int Kc = 16;     // experts
constexpr int Hc = 128;
constexpr int Dc = 64;

constexpr int CAP  = 4608;           // slots/expert = mean 4096 + 8.3 sigma
constexpr int BPE  = CAP / 64;       // 72 head blocks per expert
constexpr int NBLK = Kc * BPE;       // 1152 head blocks

constexpr float INV_LOSCALE = 1.0f / 1024.0f;

constexpr int BBW_F16 = 2048 + 3 * 16384;   // backbone weights (f16 elems)
constexpr int HWE_F16 = 3 * 16384 + 8192;   // per-expert head weights

__device__ __forceinline__ f32x16 zero16() {
    f32x16 z;
#pragma unroll
    for (int i = 0; i < 16; ++i) z[i] = 0.0f;
    return z;
}

// XOR-swizzled activation tile: 64 samples x 128 f16 (16KB).
// f16 index for (sample s, 16B-unit u): bank-conflict-floor for both the
// b128 frag reads (lanes vary s) and the b64 epilogue writes.
__device__ __forceinline__ int actOff(int s, int u) {
    return s * 128 + ((u ^ (s & 15)) << 3);
}

// ---------------------------------------------------------------------------
// Epilogue: combine hi/lo acc + bias (+ReLU) + pack f16x4 -> swizzled LDS.
// Wave `wid` produced features [32*wid, 32*wid+32) for samples 32*mt+l31.
// D-layout: acc[4*rg+j] -> feature 32*wid + 8*rg + 4*bh + j  [HW-verified].
// ---------------------------------------------------------------------------
template<bool RELU>
__device__ __forceinline__ void epi_store(
    const f32x16& aH0, const f32x16& aL0,
    const f32x16& aH1, const f32x16& aL1,
    const float* biasLds, f16* aOut, int wid, int l31, int bh)
{
#pragma unroll
    for (int rg = 0; rg < 4; ++rg) {
        const float4 bv = *(const float4*)(biasLds + 32 * wid + 8 * rg + 4 * bh);
        const float bb[4] = {bv.x, bv.y, bv.z, bv.w};
#pragma unroll
        for (int mt = 0; mt < 2; ++mt) {
            const f32x16& aH = mt ? aH1 : aH0;
            const f32x16& aL = mt ? aL1 : aL0;
            f16x4 h4;
#pragma unroll
            for (int j = 0; j < 4; ++j) {
                float v = fmaf(aL[4 * rg + j], INV_LOSCALE, aH[4 * rg + j]) + bb[j];
                if (RELU) v = fmaxf(v, 0.0f);
                h4[j] = (f16)v;
            }
            const int s = 32 * mt + l31;
            *(f16x4*)(aOut + actOff(s, 4 * wid + rg) + 4 * bh) = h4;
        }
    }
}

// ---------------------------------------------------------------------------
// One 128->128 Linear+ReLU layer; wave `wid` computes its 32-col quarter.
// W chunk layout (from prep_w): chunk nt = 4096 f16 laid out [ks][lane]:
// element (nt, ks, lane, j) = W^T[32*nt + (lane&31)][16*ks + 8*(lane>>5) + j]
// -> each f16x8 load is 1KB contiguous per wave instruction.
// ---------------------------------------------------------------------------
__device__ __forceinline__ void layer4(
    const f16* __restrict__ Wh, const f16* __restrict__ Wl,
    const float* biasLds, const f16* aIn, f16* aOut,
    int wid, int lane, int l31, int bh)
{
    const f16* ph = Wh + wid * 4096 + lane * 8;
    const f16* pl = Wl + wid * 4096 + lane * 8;

    f32x16 aH0 = zero16(), aH1 = zero16(), aL0 = zero16(), aL1 = zero16();
#pragma unroll
    for (int ks = 0; ks < 8; ++ks) {
        const f16x8 whi = *(const f16x8*)(ph + ks * 512);
        const f16x8 wlo = *(const f16x8*)(pl + ks * 512);
        const f16x8 a0 = *(const f16x8*)(aIn + actOff(l31,      2 * ks + bh));
        const f16x8 a1 = *(const f16x8*)(aIn + actOff(32 + l31, 2 * ks + bh));
        aH0 = MFMA(whi, a0, aH0);
        aH1 = MFMA(whi, a1, aH1);
        aL0 = MFMA(wlo, a0, aL0);
        aL1 = MFMA(wlo, a1, aL1);
    }
    epi_store<true>(aH0, aL0, aH1, aL1, biasLds, aOut, wid, l31, bh);
}

// ---------------------------------------------------------------------------
// Backbone: 256-thread block, 64 samples. z -> L0(K=16) -> 3x L128 -> h.
// ---------------------------------------------------------------------------
__global__ __launch_bounds__(256, 3) void backbone_mfma(
    const float* __restrict__ z,
    const f16* __restrict__ bbH, const f16* __restrict__ bbL,
    const float* __restrict__ bb0, const float* __restrict__ bb1,
    const float* __restrict__ bb2, const float* __restrict__ bb3,
    f16* __restrict__ hHi)
{
    __shared__ __attribute__((aligned(16))) f16 A[64 * 128];
    __shared__ __attribute__((aligned(16))) f16 B[64 * 128];
    __shared__ __attribute__((aligned(16))) float BIAS[512];

    const int tid = threadIdx.x;
    const int wid = tid >> 6, lane = tid & 63;
    const int l31 = lane & 31, bh = lane >> 5;
    const int s0 = blockIdx.x * 64;

    // biases -> LDS
#pragma unroll
    for (int r = 0; r < 2; ++r) {
        const int i = r * 256 + tid;
        float v;
        if      (i < 128) v = bb0[i];
        else if (i < 256) v = bb1[i - 128];
        else if (i < 384) v = bb2[i - 256];
        else              v = bb3[i - 384];
        BIAS[i] = v;
    }

    // stage z (f16, swizzled): threads 0..127, one half-row each
    if (tid < 128) {
        const int m = tid >> 1, hf = tid & 1;
        const float* zp = z + (size_t)(s0 + m) * 16 + hf * 8;
        const float4 a0 = *(const float4*)(zp);
        const float4 a1 = *(const float4*)(zp + 4);
        f16x8 t;
        t[0] = (f16)a0.x; t[1] = (f16)a0.y; t[2] = (f16)a0.z; t[3] = (f16)a0.w;
        t[4] = (f16)a1.x; t[5] = (f16)a1.y; t[6] = (f16)a1.z; t[7] = (f16)a1.w;
        *(f16x8*)(A + actOff(m, hf)) = t;
    }
    __syncthreads();

    // layer0 (K=16): one k-window
    {
        const f16x8 w0h = *(const f16x8*)(bbH + wid * 512 + lane * 8);
        const f16x8 w0l = *(const f16x8*)(bbL + wid * 512 + lane * 8);
        const f16x8 a0 = *(const f16x8*)(A + actOff(l31,      bh));
        const f16x8 a1 = *(const f16x8*)(A + actOff(32 + l31, bh));
        f32x16 aH0 = zero16(), aH1 = zero16(), aL0 = zero16(), aL1 = zero16();
        aH0 = MFMA(w0h, a0, aH0);
        aH1 = MFMA(w0h, a1, aH1);
        aL0 = MFMA(w0l, a0, aL0);
        aL1 = MFMA(w0l, a1, aL1);
        epi_store<true>(aH0, aL0, aH1, aL1, BIAS, B, wid, l31, bh);
    }
    __syncthreads();

    layer4(bbH + 2048,  bbL + 2048,  BIAS + 128, B, A, wid, lane, l31, bh);
    __syncthreads();
    layer4(bbH + 18432, bbL + 18432, BIAS + 256, A, B, wid, lane, l31, bh);
    __syncthreads();
    layer4(bbH + 34816, bbL + 34816, BIAS + 384, B, A, wid, lane, l31, bh);
    __syncthreads();

    // store h (f16 linear [b][k]) from A, coalesced-ish 16B chunks
    {
        const int m = tid >> 2, q = tid & 3;
#pragma unroll
        for (int i = 0; i < 4; ++i) {
            const f16x8 v = *(const f16x8*)(A + actOff(m, 4 * q + i));
            *(f16x8*)(hHi + (size_t)(s0 + m) * Hc + q * 32 + i * 8) = v;
        }
    }
}

// ---------------------------------------------------------------------------
// Standalone expert scatter: LDS-aggregated ranks, cursor padded to one
// cache line per expert (64B) to break the atomic herd.
// ---------------------------------------------------------------------------
__global__ void scatter_kernel(const int* __restrict__ y,
                               int* __restrict__ idxb, int* __restrict__ cursor)
{
    __shared__ int lc[Kc];
    __shared__ int lbase[Kc];
    const int tx = threadIdx.x;
    if (tx < Kc) lc[tx] = 0;
    __syncthreads();
    const int b = blockIdx.x * 256 + tx;
    const int e = y[b];
    const int r = atomicAdd(&lc[e], 1);
    __syncthreads();
    if (tx < Kc) lbase[tx] = atomicAdd(&cursor[tx * 16], lc[tx]);
    __syncthreads();
    const int slot = lbase[e] + r;
    if (slot < CAP) idxb[e * CAP + slot] = b;
}

// ---------------------------------------------------------------------------
// Heads: 256-thread block, 64 samples of ONE expert. gather -> 3x L128 ->
// final 128->64 (waves 0,1) with direct float4 stores to out[b].
// hHi aliases d_out (row-disjoint across blocks; gather precedes stores).
// ---------------------------------------------------------------------------
__global__ __launch_bounds__(256, 3) void heads_mfma(
    const f16* hHi,
    const int* __restrict__ idxb, const int* __restrict__ cursor,
    const f16* __restrict__ hH, const f16* __restrict__ hL,
    const float* __restrict__ hb0, const float* __restrict__ hb1,
    const float* __restrict__ hb2, const float* __restrict__ hb3,
    float* out)
{
    __shared__ __attribute__((aligned(16))) f16 A[64 * 128];
    __shared__ __attribute__((aligned(16))) f16 B[64 * 128];
    __shared__ __attribute__((aligned(16))) float BIAS[512];
    __shared__ int sidx[64];

    const int blk = blockIdx.x;
    const int e = blk / BPE;
    const int local0 = (blk % BPE) * 64;
    const int cnt = min(cursor[e * 16], CAP);
    const int nvalid = cnt - local0;
    if (nvalid <= 0) return;                    // uniform, before any barrier

    const int tid = threadIdx.x;
    const int wid = tid >> 6, lane = tid & 63;
    const int l31 = lane & 31, bh = lane >> 5;

    // biases -> LDS
#pragma unroll
    for (int r = 0; r < 2; ++r) {
        const int i = r * 256 + tid;
        if (i < 448) {
            float v;
            if      (i < 128) v = hb0[e * Hc + i];
            else if (i < 256) v = hb1[e * Hc + i - 128];
            else if (i < 384) v = hb2[e * Hc + i - 256];
            else              v = hb3[e * Dc + i - 384];
            BIAS[i] = v;
        }
    }
    if (tid < 64) sidx[tid] = (tid < nvalid) ? idxb[e * CAP + local0 + tid] : -1;
    __syncthreads();

    // gather h rows -> A (swizzled); zero rows for invalid slots
    {
        const int m = tid >> 2, q = tid & 3;
        const int b = sidx[m];
        if (b >= 0) {
            const f16* hp = hHi + (size_t)b * Hc + q * 32;
#pragma unroll
            for (int i = 0; i < 4; ++i)
                *(f16x8*)(A + actOff(m, 4 * q + i)) = *(const f16x8*)(hp + i * 8);
        } else {
            f16x8 zz;
#pragma unroll
            for (int j = 0; j < 8; ++j) zz[j] = (f16)0.0f;
#pragma unroll
            for (int i = 0; i < 4; ++i)
                *(f16x8*)(A + actOff(m, 4 * q + i)) = zz;
        }
    }
    __syncthreads();

    const size_t we = (size_t)e * HWE_F16;
    layer4(hH + we,         hL + we,         BIAS,       A, B, wid, lane, l31, bh);
    __syncthreads();
    layer4(hH + we + 16384, hL + we + 16384, BIAS + 128, B, A, wid, lane, l31, bh);
    __syncthreads();
    layer4(hH + we + 32768, hL + we + 32768, BIAS + 256, A, B, wid, lane, l31, bh);
    __syncthreads();

    // final 128->64 (no ReLU): waves 0,1 own the two 32-col quarters
    if (wid < 2) {
        const f16* ph = hH + we + 49152 + wid * 4096 + lane * 8;
        const f16* pl = hL + we + 49152 + wid * 4096 + lane * 8;
        f32x16 aH0 = zero16(), aH1 = zero16(), aL0 = zero16(), aL1 = zero16();
#pragma unroll
        for (int ks = 0; ks < 8; ++ks) {
            const f16x8 whi = *(const f16x8*)(ph + ks * 512);
            const f16x8 wlo = *(const f16x8*)(pl + ks * 512);
            const f16x8 a0 = *(const f16x8*)(B + actOff(l31,      2 * ks + bh));
            const f16x8 a1 = *(const f16x8*)(B + actOff(32 + l31, 2 * ks + bh));
            aH0 = MFMA(whi, a0, aH0);
            aH1 = MFMA(whi, a1, aH1);
            aL0 = MFMA(wlo, a0, aL0);
            aL1 = MFMA(wlo, a1, aL1);
        }
#pragma unroll
        for (int mt = 0; mt < 2; ++mt) {
            const int b = sidx[32 * mt + l31];
            if (b < 0) continue;
            const f32x16& aH = mt ? aH1 : aH0;
            const f32x16& aL = mt ? aL1 : aL0;
#pragma unroll
            for (int rg = 0; rg < 4; ++rg) {
                const int nb = 32 * wid + 8 * rg + 4 * bh;
                const float4 bv = *(const float4*)(BIAS + 384 + nb);
                float4 v;
                v.x = fmaf(aL[4 * rg + 0], INV_LOSCALE, aH[4 * rg + 0]) + bv.x;
                v.y = fmaf(aL[4 * rg + 1], INV_LOSCALE, aH[4 * rg + 1]) + bv.y;
                v.z = fmaf(aL[4 * rg + 2], INV_LOSCALE, aH[4 * rg + 2]) + bv.z;
                v.w = fmaf(aL[4 * rg + 3], INV_LOSCALE, aH[4 * rg + 3]) + bv.w;
                *(float4*)(out + (size_t)b * Dc + nb) = v;
            }
        }
    }
}

// ---------------------------------------------------------------------------
// Weight prep: split fp32 W[k][n] -> f16 hi + f16 (lo*1024), transposed and
// re-laid per 32-row chunk as [ks][lane]: element index within a layer =
//   (n>>5)*4096 + (k>>4)*512 + ((k>>3)&1)*256 + (n&31)*8 + (k&7)
// (layer0 K=16: (n>>5)*512 + (k>>3)*256 + (n&31)*8 + (k&7)).
// Block 0 zeroes the padded cursor (256 ints).
// ---------------------------------------------------------------------------
__global__ void prep_w(
    const float* __restrict__ bw0, const float* __restrict__ bw1,
    const float* __restrict__ bw2, const float* __restrict__ bw3,
    const float* __restrict__ hw0, const float* __restrict__ hw1,
    const float* __restrict__ hw2, const float* __restrict__ hw3,
    f16* __restrict__ bbH, f16* __restrict__ bbL,
    f16* __restrict__ hH,  f16* __restrict__ hL,
    int* __restrict__ cursor)
{
    __shared__ float T[32][33];
    const int id = blockIdx.x;
    const int tx = threadIdx.x;

    if (id == 0) cursor[tx] = 0;   // 256 padded ints

    const float* src; f16 *dh, *dl;
    int K, N, k0, n0;
    bool big;

    if (id < 52) {
        if (id < 4) {
            src = bw0; dh = bbH; dl = bbL;
            K = 16; N = 128; k0 = 0; n0 = id * 32; big = false;
        } else {
            const int t = id - 4;
            const int l = t / 16, tile = t % 16;
            const float* bws[3] = {bw1, bw2, bw3};
            src = bws[l];
            dh = bbH + 2048 + l * 16384;
            dl = bbL + 2048 + l * 16384;
            K = 128; N = 128; big = true;
            k0 = (tile >> 2) * 32; n0 = (tile & 3) * 32;
        }
    } else {
        const int t = id - 52;
        const int e = t / 56, r = t % 56;
        if (r < 48) {
            const int l = r / 16, tile = r % 16;
            const float* hws[3] = {hw0, hw1, hw2};
            src = hws[l] + (size_t)e * 16384;
            dh = hH + (size_t)e * HWE_F16 + l * 16384;
            dl = hL + (size_t)e * HWE_F16 + l * 16384;
            K = 128; N = 128; big = true;
            k0 = (tile >> 2) * 32; n0 = (tile & 3) * 32;
        } else {
            const int r2 = r - 48;
            src = hw3 + (size_t)e * 8192;
            dh = hH + (size_t)e * HWE_F16 + 49152;
            dl = hL + (size_t)e * HWE_F16 + 49152;
            K = 128; N = 64; big = true;
            k0 = (r2 >> 1) * 32; n0 = (r2 & 1) * 32;
        }
    }

    const int c = tx & 31, g = tx >> 5;
#pragma unroll
    for (int i = 0; i < 4; ++i) {
        const int row = g * 4 + i;
        if (k0 + row < K)
            T[c][row] = src[(size_t)(k0 + row) * N + n0 + c];   // T[n-local][k-local]
    }
    __syncthreads();
#pragma unroll
    for (int i = 0; i < 4; ++i) {
        const int n = n0 + g * 4 + i;
        const int k = k0 + c;
        if (k < K) {
            const float v = T[g * 4 + i][c];
            const f16 hi = (f16)v;
            const f16 lo = (f16)((v - (float)hi) * 1024.0f);
            size_t didx;
            if (big)
                didx = (size_t)(n >> 5) * 4096 + (size_t)(k >> 4) * 512
                     + ((k >> 3) & 1) * 256 + (n & 31) * 8 + (k & 7);
            else
                didx = (size_t)(n >> 5) * 512 + (size_t)(k >> 3) * 256
                     + (n & 31) * 8 + (k & 7);
            dh[didx] = hi;
            dl[didx] = lo;
        }
    }
}

// ---------------------------------------------------------------------------
extern "C" void kernel_launch(void* const* d_in, const int* in_sizes, int n_in,
                              void* d_out, int out_size, void* d_ws, size_t ws_size,
                              hipStream_t stream)
{
    const float* z   = (const float*)d_in[0];
    const int*   y   = (const int*)d_in[1];
    const float* bw0 = (const float*)d_in[2];
    const float* bb0 = (const float*)d_in[3];
    const float* bw1 = (const float*)d_in[4];
    const float* bb1 = (const float*)d_in[5];
    const float* bw2 = (const float*)d_in[6];
    const float* bb2 = (const float*)d_in[7];
    const float* bw3 = (const float*)d_in[8];
    const float* bb3 = (const float*)d_in[9];
    const float* hw0 = (const float*)d_in[10];
    const float* hb0 = (const float*)d_in[11];
    const float* hw1 = (const float*)d_in[12];
    const float* hb1 = (const float*)d_in[13];
    const float* hw2 = (const float*)d_in[14];
    const float* hb2 = (const float*)d_in[15];
    const float* hw3 = (const float*)d_in[16];
    const float* hb3 = (const float*)d_in[17];
    float* out = (float*)d_out;

    // h (f16 [B][128]) aliases d_out exactly: sample b's h row and out row
    // occupy the same 256-byte range; each heads block gathers before storing.
    f16* hHi = (f16*)d_out;

    // workspace layout (segments 256B-aligned)
    char* p = (char*)d_ws;
    f16* bbH = (f16*)p;  p += (size_t)BBW_F16 * 2;
    f16* bbL = (f16*)p;  p += (size_t)BBW_F16 * 2;
    f16* hH  = (f16*)p;  p += (size_t)Kc * HWE_F16 * 2;
    f16* hL  = (f16*)p;  p += (size_t)Kc * HWE_F16 * 2;
    int* idxb = (int*)p; p += (size_t)Kc * CAP * 4;
    int* cursor = (int*)p;                                   // 256 ints, padded

    prep_w<<<52 + Kc * 56, 256, 0, stream>>>(bw0, bw1, bw2, bw3,
                                             hw0, hw1, hw2, hw3,
                                             bbH, bbL, hH, hL, cursor);

    scatter_kernel<<<Bc / 256, 256, 0, stream>>>(y, idxb, cursor);

    backbone_mfma<<<Bc / 64, 256, 0, stream>>>(z, bbH, bbL,
                                               bb0, bb1, bb2, bb3, hHi);

    heads_mfma<<<NBLK, 256, 0, stream>>>(hHi, idxb, cursor,
                                         hH, hL, hb0, hb1, hb2, hb3, out);
}

// Round 10
// 151.256 us; speedup vs baseline: 1.5662x; 1.0186x over previous
//
#include <hip/hip_runtime.h>
#include <hip/hip_bf16.h>
#include <stdint.h>

// ---------------------------------------------------------------------------
// MappingNetwork: backbone 4x(Linear+ReLU) [16->128, 3x 128->128], then the
// selected expert head only (4 layers, last no-ReLU, 128->64).
//
// Round-10: FULL FUSION. The expert sort depends only on y, so it runs
// FIRST; then one 256-thread block carries 64 same-expert samples through
// all 8 layers end-to-end (gather z -> backbone -> head -> out). This kills
// the h global round-trip (33 MB), one kernel launch, and the d_out alias.
// Stream: memset(cursor) -> prep_w+scatter (one kernel, disjoint blocks) ->
// fused MLP. Note: top-5 "fillBufferAligned" dispatches are the harness's
// 256MB ws poison (~44 us fixed overhead in the measured window).
//
// Verified components from r9 (154 us total, occupancy fix): XOR-swizzled
// LDS activation tile (bank floor), per-wave 32-col layer quarters
// (~130 live VGPRs, 12 waves/CU at launch_bounds(256,3)), W chunks
// pre-laid [ks][lane] for 1KB/instr coalesced streams, one barrier/layer.
// Numerics (validated r3-r9, absmax 1.5259e-5): acts f16, W exact 2-term
// split w = whi + (wlo*1024)/1024, separate accumulators.
// MFMA operand swap mfma(W, act): D lane = sample, D regs = feature.
// ---------------------------------------------------------------------------

typedef _Float16 f16;
typedef __attribute__((ext_vector_type(4)))  _Float16 f16x4;
typedef __attribute__((ext_vector_type(8)))  _Float16 f16x8;
typedef __attribute__((ext_vector_type(16))) float    f32x16;
typedef uint32_t u32;

#define MFMA(a, b, c) __builtin_amdgcn_mfma_f32_32x32x16_f16((a), (b), (c), 0, 0, 0)

constexpr int Bc = 65536;
constexpr int Kc = 16;     // experts
constexpr int Hc = 128;
constexpr int Dc = 64;

constexpr int CAP  = 4608;           // slots/expert = mean 4096 + 8.3 sigma
constexpr int BPE  = CAP / 64;       // 72 blocks per expert
constexpr int NBLK = Kc * BPE;       // 1152 fused blocks

constexpr float INV_LOSCALE = 1.0f / 1024.0f;

constexpr int BBW_F16 = 2048 + 3 * 16384;   // backbone weights (f16 elems)
constexpr int HWE_F16 = 3 * 16384 + 8192;   // per-expert head weights

constexpr int PREP_BLKS = 52 + Kc * 56;     // 948 weight-prep blocks

__device__ __forceinline__ f32x16 zero16() {
    f32x16 z;
#pragma unroll
    for (int i = 0; i < 16; ++i) z[i] = 0.0f;
    return z;
}

// XOR-swizzled activation tile: 64 samples x 128 f16 (16KB).
__device__ __forceinline__ int actOff(int s, int u) {
    return s * 128 + ((u ^ (s & 15)) << 3);
}

// ---------------------------------------------------------------------------
// Epilogue: combine hi/lo acc + bias (+ReLU) + pack f16x4 -> swizzled LDS.
// D-layout: acc[4*rg+j] -> feature 32*wid + 8*rg + 4*bh + j  [HW-verified].
// ---------------------------------------------------------------------------
template<bool RELU>
__device__ __forceinline__ void epi_store(
    const f32x16& aH0, const f32x16& aL0,
    const f32x16& aH1, const f32x16& aL1,
    const float* biasLds, f16* aOut, int wid, int l31, int bh)
{
#pragma unroll
    for (int rg = 0; rg < 4; ++rg) {
        const float4 bv = *(const float4*)(biasLds + 32 * wid + 8 * rg + 4 * bh);
        const float bb[4] = {bv.x, bv.y, bv.z, bv.w};
#pragma unroll
        for (int mt = 0; mt < 2; ++mt) {
            const f32x16& aH = mt ? aH1 : aH0;
            const f32x16& aL = mt ? aL1 : aL0;
            f16x4 h4;
#pragma unroll
            for (int j = 0; j < 4; ++j) {
                float v = fmaf(aL[4 * rg + j], INV_LOSCALE, aH[4 * rg + j]) + bb[j];
                if (RELU) v = fmaxf(v, 0.0f);
                h4[j] = (f16)v;
            }
            const int s = 32 * mt + l31;
            *(f16x4*)(aOut + actOff(s, 4 * wid + rg) + 4 * bh) = h4;
        }
    }
}

// ---------------------------------------------------------------------------
// One 128->128 Linear+ReLU layer; wave `wid` computes its 32-col quarter.
// W chunk layout: [ks][lane] -> each f16x8 load is 1KB contiguous per wave.
// ---------------------------------------------------------------------------
__device__ __forceinline__ void layer4(
    const f16* __restrict__ Wh, const f16* __restrict__ Wl,
    const float* biasLds, const f16* aIn, f16* aOut,
    int wid, int lane, int l31, int bh)
{
    const f16* ph = Wh + wid * 4096 + lane * 8;
    const f16* pl = Wl + wid * 4096 + lane * 8;

    f32x16 aH0 = zero16(), aH1 = zero16(), aL0 = zero16(), aL1 = zero16();
#pragma unroll
    for (int ks = 0; ks < 8; ++ks) {
        const f16x8 whi = *(const f16x8*)(ph + ks * 512);
        const f16x8 wlo = *(const f16x8*)(pl + ks * 512);
        const f16x8 a0 = *(const f16x8*)(aIn + actOff(l31,      2 * ks + bh));
        const f16x8 a1 = *(const f16x8*)(aIn + actOff(32 + l31, 2 * ks + bh));
        aH0 = MFMA(whi, a0, aH0);
        aH1 = MFMA(whi, a1, aH1);
        aL0 = MFMA(wlo, a0, aL0);
        aL1 = MFMA(wlo, a1, aL1);
    }
    epi_store<true>(aH0, aL0, aH1, aL1, biasLds, aOut, wid, l31, bh);
}

// ---------------------------------------------------------------------------
// Fused MLP: one block = 64 samples of ONE expert through all 8 layers.
// gather z -> backbone L0..L3 -> head L0..L2 -> final 128->64 -> out.
// ---------------------------------------------------------------------------
__global__ __launch_bounds__(256, 3) void fused_mlp(
    const float* __restrict__ z,
    const int* __restrict__ idxb, const int* __restrict__ cursor,
    const f16* __restrict__ bbH, const f16* __restrict__ bbL,
    const float* __restrict__ bb0, const float* __restrict__ bb1,
    const float* __restrict__ bb2, const float* __restrict__ bb3,
    const f16* __restrict__ hH, const f16* __restrict__ hL,
    const float* __restrict__ hb0, const float* __restrict__ hb1,
    const float* __restrict__ hb2, const float* __restrict__ hb3,
    float* __restrict__ out)
{
    __shared__ __attribute__((aligned(16))) f16 A[64 * 128];
    __shared__ __attribute__((aligned(16))) f16 B[64 * 128];
    __shared__ __attribute__((aligned(16))) float BIAS[960];
    __shared__ int sidx[64];

    const int blk = blockIdx.x;
    const int e = blk / BPE;
    const int local0 = (blk % BPE) * 64;
    const int cnt = min(cursor[e * 16], CAP);
    const int nvalid = cnt - local0;
    if (nvalid <= 0) return;                    // uniform, before any barrier

    const int tid = threadIdx.x;
    const int wid = tid >> 6, lane = tid & 63;
    const int l31 = lane & 31, bh = lane >> 5;

    // biases -> LDS: [0,512) backbone, [512,960) head of expert e
#pragma unroll
    for (int r = 0; r < 4; ++r) {
        const int i = r * 256 + tid;
        if (i < 960) {
            float v;
            if      (i < 128) v = bb0[i];
            else if (i < 256) v = bb1[i - 128];
            else if (i < 384) v = bb2[i - 256];
            else if (i < 512) v = bb3[i - 384];
            else if (i < 640) v = hb0[e * Hc + i - 512];
            else if (i < 768) v = hb1[e * Hc + i - 640];
            else if (i < 896) v = hb2[e * Hc + i - 768];
            else              v = hb3[e * Dc + i - 896];
            BIAS[i] = v;
        }
    }
    if (tid < 64) sidx[tid] = (tid < nvalid) ? idxb[e * CAP + local0 + tid] : -1;
    __syncthreads();

    // gather z rows -> A (f16, swizzled). 4 threads per sample, 4 floats each.
    {
        const int m = tid >> 2, q = tid & 3;
        const int b = sidx[m];
        f16x4 t;
        if (b >= 0) {
            const float4 v = *(const float4*)(z + (size_t)b * 16 + q * 4);
            t[0] = (f16)v.x; t[1] = (f16)v.y; t[2] = (f16)v.z; t[3] = (f16)v.w;
        } else {
            t[0] = t[1] = t[2] = t[3] = (f16)0.0f;
        }
        *(f16x4*)(A + actOff(m, q >> 1) + (q & 1) * 4) = t;
    }
    __syncthreads();

    // backbone layer0 (K=16): one k-window. A -> B
    {
        const f16x8 w0h = *(const f16x8*)(bbH + wid * 512 + lane * 8);
        const f16x8 w0l = *(const f16x8*)(bbL + wid * 512 + lane * 8);
        const f16x8 a0 = *(const f16x8*)(A + actOff(l31,      bh));
        const f16x8 a1 = *(const f16x8*)(A + actOff(32 + l31, bh));
        f32x16 aH0 = zero16(), aH1 = zero16(), aL0 = zero16(), aL1 = zero16();
        aH0 = MFMA(w0h, a0, aH0);
        aH1 = MFMA(w0h, a1, aH1);
        aL0 = MFMA(w0l, a0, aL0);
        aL1 = MFMA(w0l, a1, aL1);
        epi_store<true>(aH0, aL0, aH1, aL1, BIAS, B, wid, l31, bh);
    }
    __syncthreads();

    // backbone layers 1-3: B -> A -> B -> A
    layer4(bbH + 2048,  bbL + 2048,  BIAS + 128, B, A, wid, lane, l31, bh);
    __syncthreads();
    layer4(bbH + 18432, bbL + 18432, BIAS + 256, A, B, wid, lane, l31, bh);
    __syncthreads();
    layer4(bbH + 34816, bbL + 34816, BIAS + 384, B, A, wid, lane, l31, bh);
    __syncthreads();

    // head layers 0-2: A -> B -> A -> B
    const size_t we = (size_t)e * HWE_F16;
    layer4(hH + we,         hL + we,         BIAS + 512, A, B, wid, lane, l31, bh);
    __syncthreads();
    layer4(hH + we + 16384, hL + we + 16384, BIAS + 640, B, A, wid, lane, l31, bh);
    __syncthreads();
    layer4(hH + we + 32768, hL + we + 32768, BIAS + 768, A, B, wid, lane, l31, bh);
    __syncthreads();

    // final 128->64 (no ReLU): waves 0,1 own the two 32-col quarters
    if (wid < 2) {
        const f16* ph = hH + we + 49152 + wid * 4096 + lane * 8;
        const f16* pl = hL + we + 49152 + wid * 4096 + lane * 8;
        f32x16 aH0 = zero16(), aH1 = zero16(), aL0 = zero16(), aL1 = zero16();
#pragma unroll
        for (int ks = 0; ks < 8; ++ks) {
            const f16x8 whi = *(const f16x8*)(ph + ks * 512);
            const f16x8 wlo = *(const f16x8*)(pl + ks * 512);
            const f16x8 a0 = *(const f16x8*)(B + actOff(l31,      2 * ks + bh));
            const f16x8 a1 = *(const f16x8*)(B + actOff(32 + l31, 2 * ks + bh));
            aH0 = MFMA(whi, a0, aH0);
            aH1 = MFMA(whi, a1, aH1);
            aL0 = MFMA(wlo, a0, aL0);
            aL1 = MFMA(wlo, a1, aL1);
        }
#pragma unroll
        for (int mt = 0; mt < 2; ++mt) {
            const int b = sidx[32 * mt + l31];
            if (b < 0) continue;
            const f32x16& aH = mt ? aH1 : aH0;
            const f32x16& aL = mt ? aL1 : aL0;
#pragma unroll
            for (int rg = 0; rg < 4; ++rg) {
                const int nb = 32 * wid + 8 * rg + 4 * bh;
                const float4 bv = *(const float4*)(BIAS + 896 + nb);
                float4 v;
                v.x = fmaf(aL[4 * rg + 0], INV_LOSCALE, aH[4 * rg + 0]) + bv.x;
                v.y = fmaf(aL[4 * rg + 1], INV_LOSCALE, aH[4 * rg + 1]) + bv.y;
                v.z = fmaf(aL[4 * rg + 2], INV_LOSCALE, aH[4 * rg + 2]) + bv.z;
                v.w = fmaf(aL[4 * rg + 3], INV_LOSCALE, aH[4 * rg + 3]) + bv.w;
                *(float4*)(out + (size_t)b * Dc + nb) = v;
            }
        }
    }
}

// ---------------------------------------------------------------------------
// prep_w + scatter in one kernel (disjoint block ranges; scatter blocks only
// touch y/idxb/cursor, cursor pre-zeroed by hipMemsetAsync).
// Weight prep: split fp32 W[k][n] -> f16 hi + f16 (lo*1024), transposed and
// re-laid per 32-row chunk as [ks][lane].
// ---------------------------------------------------------------------------
__global__ void prep_scatter(
    const float* __restrict__ bw0, const float* __restrict__ bw1,
    const float* __restrict__ bw2, const float* __restrict__ bw3,
    const float* __restrict__ hw0, const float* __restrict__ hw1,
    const float* __restrict__ hw2, const float* __restrict__ hw3,
    f16* __restrict__ bbH, f16* __restrict__ bbL,
    f16* __restrict__ hH,  f16* __restrict__ hL,
    const int* __restrict__ y, int* __restrict__ idxb, int* __restrict__ cursor)
{
    __shared__ float T[32][33];
    __shared__ int lc[Kc];
    __shared__ int lbase[Kc];
    const int id = blockIdx.x;
    const int tx = threadIdx.x;

    if (id >= PREP_BLKS) {
        // ---- scatter block ----
        if (tx < Kc) lc[tx] = 0;
        __syncthreads();
        const int b = (id - PREP_BLKS) * 256 + tx;
        const int e = y[b];
        const int r = atomicAdd(&lc[e], 1);
        __syncthreads();
        if (tx < Kc) lbase[tx] = atomicAdd(&cursor[tx * 16], lc[tx]);
        __syncthreads();
        const int slot = lbase[e] + r;
        if (slot < CAP) idxb[e * CAP + slot] = b;
        return;
    }

    // ---- weight-prep block ----
    const float* src; f16 *dh, *dl;
    int K, N, k0, n0;
    bool big;

    if (id < 52) {
        if (id < 4) {
            src = bw0; dh = bbH; dl = bbL;
            K = 16; N = 128; k0 = 0; n0 = id * 32; big = false;
        } else {
            const int t = id - 4;
            const int l = t / 16, tile = t % 16;
            const float* bws[3] = {bw1, bw2, bw3};
            src = bws[l];
            dh = bbH + 2048 + l * 16384;
            dl = bbL + 2048 + l * 16384;
            K = 128; N = 128; big = true;
            k0 = (tile >> 2) * 32; n0 = (tile & 3) * 32;
        }
    } else {
        const int t = id - 52;
        const int e = t / 56, r = t % 56;
        if (r < 48) {
            const int l = r / 16, tile = r % 16;
            const float* hws[3] = {hw0, hw1, hw2};
            src = hws[l] + (size_t)e * 16384;
            dh = hH + (size_t)e * HWE_F16 + l * 16384;
            dl = hL + (size_t)e * HWE_F16 + l * 16384;
            K = 128; N = 128; big = true;
            k0 = (tile >> 2) * 32; n0 = (tile & 3) * 32;
        } else {
            const int r2 = r - 48;
            src = hw3 + (size_t)e * 8192;
            dh = hH + (size_t)e * HWE_F16 + 49152;
            dl = hL + (size_t)e * HWE_F16 + 49152;
            K = 128; N = 64; big = true;
            k0 = (r2 >> 1) * 32; n0 = (r2 & 1) * 32;
        }
    }

    const int c = tx & 31, g = tx >> 5;
#pragma unroll
    for (int i = 0; i < 4; ++i) {
        const int row = g * 4 + i;
        if (k0 + row < K)
            T[c][row] = src[(size_t)(k0 + row) * N + n0 + c];   // T[n-local][k-local]
    }
    __syncthreads();
#pragma unroll
    for (int i = 0; i < 4; ++i) {
        const int n = n0 + g * 4 + i;
        const int k = k0 + c;
        if (k < K) {
            const float v = T[g * 4 + i][c];
            const f16 hi = (f16)v;
            const f16 lo = (f16)((v - (float)hi) * 1024.0f);
            size_t didx;
            if (big)
                didx = (size_t)(n >> 5) * 4096 + (size_t)(k >> 4) * 512
                     + ((k >> 3) & 1) * 256 + (n & 31) * 8 + (k & 7);
            else
                didx = (size_t)(n >> 5) * 512 + (size_t)(k >> 3) * 256
                     + (n & 31) * 8 + (k & 7);
            dh[didx] = hi;
            dl[didx] = lo;
        }
    }
}

// ---------------------------------------------------------------------------
extern "C" void kernel_launch(void* const* d_in, const int* in_sizes, int n_in,
                              void* d_out, int out_size, void* d_ws, size_t ws_size,
                              hipStream_t stream)
{
    const float* z   = (const float*)d_in[0];
    const int*   y   = (const int*)d_in[1];
    const float* bw0 = (const float*)d_in[2];
    const float* bb0 = (const float*)d_in[3];
    const float* bw1 = (const float*)d_in[4];
    const float* bb1 = (const float*)d_in[5];
    const float* bw2 = (const float*)d_in[6];
    const float* bb2 = (const float*)d_in[7];
    const float* bw3 = (const float*)d_in[8];
    const float* bb3 = (const float*)d_in[9];
    const float* hw0 = (const float*)d_in[10];
    const float* hb0 = (const float*)d_in[11];
    const float* hw1 = (const float*)d_in[12];
    const float* hb1 = (const float*)d_in[13];
    const float* hw2 = (const float*)d_in[14];
    const float* hb2 = (const float*)d_in[15];
    const float* hw3 = (const float*)d_in[16];
    const float* hb3 = (const float*)d_in[17];
    float* out = (float*)d_out;

    // workspace layout (segments 256B-aligned)
    char* p = (char*)d_ws;
    f16* bbH = (f16*)p;  p += (size_t)BBW_F16 * 2;
    f16* bbL = (f16*)p;  p += (size_t)BBW_F16 * 2;
    f16* hH  = (f16*)p;  p += (size_t)Kc * HWE_F16 * 2;
    f16* hL  = (f16*)p;  p += (size_t)Kc * HWE_F16 * 2;
    int* idxb = (int*)p; p += (size_t)Kc * CAP * 4;
    int* cursor = (int*)p;                                   // 256 ints, padded

    hipMemsetAsync(cursor, 0, 256 * sizeof(int), stream);

    prep_scatter<<<PREP_BLKS + Bc / 256, 256, 0, stream>>>(
        bw0, bw1, bw2, bw3, hw0, hw1, hw2, hw3,
        bbH, bbL, hH, hL, y, idxb, cursor);

    fused_mlp<<<NBLK, 256, 0, stream>>>(
        z, idxb, cursor, bbH, bbL, bb0, bb1, bb2, bb3,
        hH, hL, hb0, hb1, hb2, hb3, out);
}